// Round 4
// baseline (1757.143 us; speedup 1.0000x reference)
//
#include <hip/hip_runtime.h>
#include <math.h>

// Problem constants
constexpr int NB = 2, NL = 2048, ND = 1024, NH = 4;
constexpr int NCHK = 64;            // L / 32
constexpr int NBL = NB * NL;        // 4096
#define BLDSZ (NB * NL * ND)        // 4194304

// per-chunk packed operand file (shorts): [W 8192 | Q 8192 | Kt 8192 | Ut 8192 | At 1024 | pad]
constexpr int OPS_CH = 36864;       // shorts = 72 KB = 72 x 1KB staging insts

// ---- static device scratch ----
__device__ float g_qlin[BLDSZ];
__device__ float g_klin[BLDSZ];
__device__ float g_vlin[BLDSZ];
__device__ float g_q[BLDSZ];      // post conv+silu (fp32, prep input)
__device__ float g_k[BLDSZ];
__device__ float g_v[BLDSZ];
__device__ float g_delta[BLDSZ];  // (B,L,H,DV)
__device__ float g_fs[BLDSZ];
__device__ float g_fl[BLDSZ];
__device__ float g_xw1[BLDSZ];    // x @ W1[:1024,:]
__device__ float g_omix[BLDSZ];
__device__ float g_beta[NBL * NH];
__device__ float g_stats[NBL * NH * 16];
__device__ float g_p[NBL * NH * 4];
__device__ unsigned short g_ops[(size_t)8 * 64 * OPS_CH];  // 37.7 MB

__device__ __forceinline__ float sigmoidf(float x) { return 1.f / (1.f + expf(-x)); }

__device__ __forceinline__ unsigned short f2bf(float f) {
  union { float f; unsigned int u; } v; v.f = f;
  unsigned int r = v.u + 0x7FFFu + ((v.u >> 16) & 1u);   // RNE
  return (unsigned short)(r >> 16);
}
__device__ __forceinline__ float bf2f(unsigned int bits16) {
  union { unsigned int u; float f; } v; v.u = bits16 << 16; return v.f;
}
__device__ __forceinline__ unsigned int packbf(float a, float b) {
  return (unsigned int)f2bf(a) | ((unsigned int)f2bf(b) << 16);
}

typedef __attribute__((ext_vector_type(8))) short short8v;   // 8 bf16 (4 VGPR)
typedef __attribute__((ext_vector_type(16))) float f32x16;   // MFMA 32x32 accum

__device__ __forceinline__ unsigned int cvtpk(float lo, float hi) {
  unsigned int r;
  asm("v_cvt_pk_bf16_f32 %0, %1, %2" : "=v"(r) : "v"(lo), "v"(hi));
  return r;
}

// C-layout f32x16 (col=l31, row=(e&3)+8*(e>>2)+4*lhi) -> two K-slice B-frags (k0..15, k16..31)
__device__ __forceinline__ void mkfrag(const f32x16 v, short8v& fb0, short8v& fb1) {
  unsigned int P0 = cvtpk(v[0], v[1]),   P1 = cvtpk(v[2], v[3]);
  unsigned int P2 = cvtpk(v[4], v[5]),   P3 = cvtpk(v[6], v[7]);
  unsigned int P4 = cvtpk(v[8], v[9]),   P5 = cvtpk(v[10], v[11]);
  unsigned int P6 = cvtpk(v[12], v[13]), P7 = cvtpk(v[14], v[15]);
  asm("v_permlane32_swap_b32 %0, %1" : "+v"(P0), "+v"(P2));
  asm("v_permlane32_swap_b32 %0, %1" : "+v"(P1), "+v"(P3));
  asm("v_permlane32_swap_b32 %0, %1" : "+v"(P4), "+v"(P6));
  asm("v_permlane32_swap_b32 %0, %1" : "+v"(P5), "+v"(P7));
  unsigned int f0[4] = {P0, P1, P2, P3}, f1[4] = {P4, P5, P6, P7};
  fb0 = *(short8v*)f0; fb1 = *(short8v*)f1;
}

// ================= SGEMM: C[4096,1024] = A[4096,1024] * B[1024,1024] =================
__global__ __launch_bounds__(256) void sgemm_kernel(const float* __restrict__ Aext,
                                                    const float* __restrict__ Bw,
                                                    float* __restrict__ Cext, int sel) {
  __shared__ float As[16][132];
  __shared__ float Bs[16][132];
  const float* A = (sel == 4) ? g_omix : Aext;
  float* C;
  if (sel == 0) C = g_qlin;
  else if (sel == 1) C = g_klin;
  else if (sel == 2) C = g_vlin;
  else if (sel == 3) C = g_xw1;
  else C = Cext;

  const int t = threadIdx.x;
  const int tx = t & 15, ty = t >> 4;
  const int n0 = blockIdx.x * 128, m0 = blockIdx.y * 128;
  float acc[8][8];
#pragma unroll
  for (int i = 0; i < 8; ++i)
#pragma unroll
    for (int j = 0; j < 8; ++j) acc[i][j] = 0.f;

  for (int k0 = 0; k0 < 1024; k0 += 16) {
#pragma unroll
    for (int i = 0; i < 2; ++i) {
      int j = t + i * 256;
      int m = j >> 2, k4 = (j & 3) << 2;
      float4 av = *(const float4*)&A[(size_t)(m0 + m) * 1024 + k0 + k4];
      As[k4 + 0][m] = av.x; As[k4 + 1][m] = av.y; As[k4 + 2][m] = av.z; As[k4 + 3][m] = av.w;
    }
#pragma unroll
    for (int i = 0; i < 2; ++i) {
      int j = t + i * 256;
      int kk = j >> 5, n4 = (j & 31) << 2;
      *(float4*)&Bs[kk][n4] = *(const float4*)&Bw[(size_t)(k0 + kk) * 1024 + n0 + n4];
    }
    __syncthreads();
#pragma unroll
    for (int kk = 0; kk < 16; ++kk) {
      float4 a0 = *(const float4*)&As[kk][ty * 8];
      float4 a1 = *(const float4*)&As[kk][ty * 8 + 4];
      float4 b0 = *(const float4*)&Bs[kk][tx * 4];
      float4 b1 = *(const float4*)&Bs[kk][64 + tx * 4];
      float av[8] = {a0.x, a0.y, a0.z, a0.w, a1.x, a1.y, a1.z, a1.w};
      float bv[8] = {b0.x, b0.y, b0.z, b0.w, b1.x, b1.y, b1.z, b1.w};
#pragma unroll
      for (int i = 0; i < 8; ++i)
#pragma unroll
        for (int j = 0; j < 8; ++j) acc[i][j] += av[i] * bv[j];
    }
    __syncthreads();
  }
#pragma unroll
  for (int i = 0; i < 8; ++i) {
    size_t row = (size_t)(m0 + ty * 8 + i) * 1024 + n0;
    float4 r0, r1;
    r0.x = acc[i][0]; r0.y = acc[i][1]; r0.z = acc[i][2]; r0.w = acc[i][3];
    r1.x = acc[i][4]; r1.y = acc[i][5]; r1.z = acc[i][6]; r1.w = acc[i][7];
    *(float4*)&C[row + tx * 4] = r0;
    *(float4*)&C[row + 64 + tx * 4] = r1;
  }
}

// ================= causal depthwise conv (K=4) + SiLU =================
__global__ __launch_bounds__(256) void conv_silu_kernel(const float* __restrict__ cw, int sel) {
  const float* in = (sel == 0) ? g_qlin : (sel == 1) ? g_klin : g_vlin;
  float* out = (sel == 0) ? g_q : (sel == 1) ? g_k : g_v;
  int idx = blockIdx.x * 256 + threadIdx.x;
  int c = idx & (ND - 1);
  int bl = idx >> 10;
  int l = bl & (NL - 1);
  float w0 = cw[c * 4 + 0], w1 = cw[c * 4 + 1], w2 = cw[c * 4 + 2], w3 = cw[c * 4 + 3];
  float acc = w3 * in[(size_t)bl * ND + c];
  if (l >= 1) acc += w2 * in[(size_t)(bl - 1) * ND + c];
  if (l >= 2) acc += w1 * in[(size_t)(bl - 2) * ND + c];
  if (l >= 3) acc += w0 * in[(size_t)(bl - 3) * ND + c];
  out[idx] = acc * sigmoidf(acc);
}

// ================= beta = sigmoid(x @ Wb) =================
__global__ __launch_bounds__(256) void beta_kernel(const float* __restrict__ x,
                                                   const float* __restrict__ Wb) {
  int bl = blockIdx.x;
  int h = threadIdx.x >> 6, lane = threadIdx.x & 63;
  const float* xr = x + (size_t)bl * ND;
  float acc = 0.f;
  for (int d = lane; d < ND; d += 64) acc += xr[d] * Wb[d * 4 + h];
#pragma unroll
  for (int off = 32; off; off >>= 1) acc += __shfl_xor(acc, off);
  if (lane == 0) g_beta[bl * 4 + h] = sigmoidf(acc);
}

// ================= FIR short (K=5) =================
__global__ __launch_bounds__(256) void fir_short_kernel(const float* __restrict__ filt) {
  int idx = blockIdx.x * 256 + threadIdx.x;
  int c = idx & (ND - 1);
  int bl = idx >> 10;
  int l = bl & (NL - 1);
  const float* fp = filt + c * 5;
  float acc = 0.f;
#pragma unroll
  for (int tap = 0; tap < 5; ++tap) {
    int ls = l + tap - 4;
    if (ls >= 0) acc += fp[tap] * g_v[(size_t)(bl + tap - 4) * ND + c];
  }
  g_fs[idx] = acc;
}

// ================= FIR long (K=64) — register filter + unrolled scatter =================
__global__ __launch_bounds__(256) void fir_long_kernel(const float* __restrict__ filt) {
  int blk = blockIdx.x;
  int cbk = blk & 3, lb = (blk >> 2) & 63, b = blk >> 8;
  int t = threadIdx.x;
  int c = cbk * 256 + t;
  float ff[64];
#pragma unroll
  for (int i = 0; i < 16; ++i)
    *(float4*)&ff[i * 4] = *(const float4*)&filt[(size_t)c * 64 + i * 4];
  float acc[32];
#pragma unroll
  for (int i = 0; i < 32; ++i) acc[i] = 0.f;
  const float* vb = g_v + (size_t)b * NL * ND + c;
  const int l0 = lb * 32;
#pragma unroll
  for (int d = 0; d < 95; ++d) {
    int lr = l0 - 63 + d;
    float vv = (lr >= 0) ? vb[(size_t)lr * ND] : 0.f;
    const int lo = (d > 63) ? (d - 63) : 0;
    const int hi = (d < 31) ? d : 31;
#pragma unroll
    for (int li = lo; li <= hi; ++li) acc[li] += ff[d - li] * vv;
  }
  float* ob = g_fl + ((size_t)(b * NL + l0)) * ND + c;
#pragma unroll
  for (int li = 0; li < 32; ++li) ob[(size_t)li * ND] = acc[li];
}

// ================= delta-rule chunk prep =================
// Emits per-chunk packed operand file g_ops in MFMA-fragment-major order:
//   W  [0)     : frag(st,j) lane(lhi*32+l31) e -> w[l31][st*32+j*16+lhi*8+e]
//   Q  [8192)  : same for qn
//   Kt [16384) : frag(st,j) lane -> kn[j*16+lhi*8+e][st*32+l31]
//   Ut [24576) : frag(q,g) lane, 4 shorts i -> u[8g+4lhi+i][q*32+l31]
//   At [32768) : frag(j) lane e -> attn[l31][j*16+lhi*8+e]
__global__ __launch_bounds__(256) void delta_prep_kernel() {
  __shared__ float X[32][260];
  __shared__ float Y[32][260];
  __shared__ float Am[32][33];
  __shared__ float Tm[32][33];
  __shared__ float bet[32];
  int blk = blockIdx.x;                  // cblk = (b*4+h)*64 + n
  int n = blk & 63, h = (blk >> 6) & 3, b = blk >> 8;
  int t = threadIdx.x;
  size_t rowbase = (size_t)(b * NL + n * 32);
  size_t obase = (size_t)blk * OPS_CH;
  const int st_ = t >> 5, j_ = (t >> 4) & 1, lh_ = (t >> 3) & 1, e_ = t & 7;
  const int l31_ = t & 31;

  // load q->X, k->Y
#pragma unroll
  for (int i = 0; i < 8; ++i) {
    int j = t + i * 256;
    int r = j >> 6, d4 = (j & 63) << 2;
    size_t gi = (rowbase + r) * ND + h * 256 + d4;
    *(float4*)&X[r][d4] = *(const float4*)&g_q[gi];
    *(float4*)&Y[r][d4] = *(const float4*)&g_k[gi];
  }
  if (t < 32) bet[t] = g_beta[(rowbase + t) * 4 + h];
  __syncthreads();

  // row l2norm (8 lanes per row), LDS only
  {
    int wv = t >> 6, lane = t & 63;
    int r = wv * 8 + (lane >> 3), sub = lane & 7;
    float sq = 0.f, sk = 0.f;
#pragma unroll
    for (int m4 = 0; m4 < 8; ++m4) {
      float4 a = *(const float4*)&X[r][sub * 32 + m4 * 4];
      float4 bb = *(const float4*)&Y[r][sub * 32 + m4 * 4];
      sq += a.x * a.x + a.y * a.y + a.z * a.z + a.w * a.w;
      sk += bb.x * bb.x + bb.y * bb.y + bb.z * bb.z + bb.w * bb.w;
    }
    sq += __shfl_xor(sq, 1); sq += __shfl_xor(sq, 2); sq += __shfl_xor(sq, 4);
    sk += __shfl_xor(sk, 1); sk += __shfl_xor(sk, 2); sk += __shfl_xor(sk, 4);
    float rq = rsqrtf(sq + 1e-6f), rk = rsqrtf(sk + 1e-6f);
#pragma unroll
    for (int m4 = 0; m4 < 8; ++m4) {
      float4 a = *(const float4*)&X[r][sub * 32 + m4 * 4];
      a.x *= rq; a.y *= rq; a.z *= rq; a.w *= rq;
      *(float4*)&X[r][sub * 32 + m4 * 4] = a;
      float4 bb = *(const float4*)&Y[r][sub * 32 + m4 * 4];
      bb.x *= rk; bb.y *= rk; bb.z *= rk; bb.w *= rk;
      *(float4*)&Y[r][sub * 32 + m4 * 4] = bb;
    }
  }
  __syncthreads();

  // attn = incl_lower(qn kn^T) -> At region
#pragma unroll
  for (int i = 0; i < 4; ++i) {
    int pr = t + i * 256;
    int r = pr >> 5, s = pr & 31;
    float acc = 0.f;
    if (s <= r) {
#pragma unroll 16
      for (int d4 = 0; d4 < 64; ++d4) {
        float4 a = *(const float4*)&X[r][d4 * 4];
        float4 bb = *(const float4*)&Y[s][d4 * 4];
        acc += a.x * bb.x + a.y * bb.y + a.z * bb.z + a.w * bb.w;
      }
    }
    g_ops[obase + 32768 + (((s >> 4) * 64) + ((s >> 3) & 1) * 32 + r) * 8 + (s & 7)] = f2bf(acc);
  }

  // qn -> Q region; kn -> Kt region (thread t owns column d = t)
  {
    size_t qb = obase + 8192 + (size_t)(((st_ * 2 + j_) * 64) + lh_ * 32) * 8 + e_;
#pragma unroll 8
    for (int r = 0; r < 32; ++r)
      g_ops[qb + r * 8] = f2bf(X[r][t]);
#pragma unroll
    for (int j = 0; j < 2; ++j)
#pragma unroll
      for (int lh = 0; lh < 2; ++lh) {
        int kr0 = j * 16 + lh * 8;
        uint4 v;
        v.x = packbf(Y[kr0 + 0][t], Y[kr0 + 1][t]);
        v.y = packbf(Y[kr0 + 2][t], Y[kr0 + 3][t]);
        v.z = packbf(Y[kr0 + 4][t], Y[kr0 + 5][t]);
        v.w = packbf(Y[kr0 + 6][t], Y[kr0 + 7][t]);
        *(uint4*)&g_ops[obase + 16384 + (size_t)(((st_ * 2 + j) * 64) + lh * 32 + l31_) * 8] = v;
      }
  }
  __syncthreads();

  // X <- k_beta
#pragma unroll
  for (int i = 0; i < 8; ++i) {
    int j = t + i * 256;
    int r = j >> 6, d4 = (j & 63) << 2;
    float be = bet[r];
    float4 bb = *(const float4*)&Y[r][d4];
    bb.x *= be; bb.y *= be; bb.z *= be; bb.w *= be;
    *(float4*)&X[r][d4] = bb;
  }
  __syncthreads();

  // A = strict_lower(kb kn^T)
#pragma unroll
  for (int i = 0; i < 4; ++i) {
    int pr = t + i * 256;
    int r = pr >> 5, s = pr & 31;
    float acc = 0.f;
    if (s < r) {
#pragma unroll 16
      for (int d4 = 0; d4 < 64; ++d4) {
        float4 a = *(const float4*)&X[r][d4 * 4];
        float4 bb = *(const float4*)&Y[s][d4 * 4];
        acc += a.x * bb.x + a.y * bb.y + a.z * bb.z + a.w * bb.w;
      }
    }
    Am[r][s] = acc;
  }
  __syncthreads();

  // T = (I+A)^-1 forward substitution (lane j owns column j)
  if (t < 32) {
    int j = t;
    for (int i = 0; i < 32; ++i) {
      float a = (i == j) ? 1.f : 0.f;
      for (int m = j; m < i; ++m) a -= Am[i][m] * Tm[m][j];
      Tm[i][j] = a;
    }
  }
  __syncthreads();

  // w = T @ kb -> W region (thread t owns dk-column t)
  {
    float acc[32];
#pragma unroll
    for (int r = 0; r < 32; ++r) acc[r] = 0.f;
#pragma unroll
    for (int m = 0; m < 32; ++m) {
      float xv = X[m][t];
#pragma unroll
      for (int r = m; r < 32; ++r) acc[r] += Tm[r][m] * xv;
    }
    size_t wb = obase + (size_t)(((st_ * 2 + j_) * 64) + lh_ * 32) * 8 + e_;
#pragma unroll 8
    for (int r = 0; r < 32; ++r)
      g_ops[wb + r * 8] = f2bf(acc[r]);
  }
  // Y <- v*beta
#pragma unroll
  for (int i = 0; i < 8; ++i) {
    int j = t + i * 256;
    int r = j >> 6, d4 = (j & 63) << 2;
    size_t gi = (rowbase + r) * ND + h * 256 + d4;
    float be = bet[r];
    float4 vv = *(const float4*)&g_v[gi];
    vv.x *= be; vv.y *= be; vv.z *= be; vv.w *= be;
    *(float4*)&Y[r][d4] = vv;
  }
  __syncthreads();

  // u = T @ vb -> Ut region (thread t owns dv-column t)
  {
    float acc[32];
#pragma unroll
    for (int r = 0; r < 32; ++r) acc[r] = 0.f;
#pragma unroll
    for (int m = 0; m < 32; ++m) {
      float yv = Y[m][t];
#pragma unroll
      for (int r = m; r < 32; ++r) acc[r] += Tm[r][m] * yv;
    }
    int q = t >> 5;
#pragma unroll
    for (int g = 0; g < 4; ++g)
#pragma unroll
      for (int lh = 0; lh < 2; ++lh) {
        int kr0 = 8 * g + 4 * lh;
        uint2 v;
        v.x = packbf(acc[kr0 + 0], acc[kr0 + 1]);
        v.y = packbf(acc[kr0 + 2], acc[kr0 + 3]);
        *(uint2*)&g_ops[obase + 24576 + (size_t)(((q * 4 + g) * 64) + lh * 32 + l31_) * 4] = v;
      }
  }
}

// ================= delta-rule scan — 8 blocks x 4 waves, LDS dbuf + counted vmcnt =================
// Block = one (b,h) chain; wave w owns dv-blocks {2w, 2w+1} (64 dv cols; Sacc 2x8 f32x16).
// Per step: stage next chunk (global_load_lds x18/wave) -> vmcnt(18) -> barrier ->
// compute (conflict-free frag-major ds_reads + 100 MFMA/wave) -> lgkmcnt(0) -> barrier.
__global__ __launch_bounds__(256, 1) void delta_scan_mfma() {
  __shared__ unsigned short sOps[2][OPS_CH];
  const int bh = blockIdx.x;
  const int b = bh >> 2, h = bh & 3;
  const int t = threadIdx.x;
  const int w = t >> 6, lane = t & 63;
  const int l31 = lane & 31, lhi = lane >> 5;
  const int dvb0 = w * 2;

  f32x16 S0[8], S1[8];
#pragma unroll
  for (int st = 0; st < 8; ++st)
#pragma unroll
    for (int e = 0; e < 16; ++e) { S0[st][e] = 0.f; S1[st][e] = 0.f; }

  const unsigned short* ops = g_ops + (size_t)bh * 64 * OPS_CH;

  // prologue: stage chunk 0 into buf 0
#pragma unroll
  for (int k = 0; k < 18; ++k) {
    int i = w * 18 + k;
    const unsigned short* g = ops + (size_t)i * 512 + lane * 8;
    unsigned short* l = &sOps[0][i * 512];
    __builtin_amdgcn_global_load_lds((const __attribute__((address_space(1))) unsigned int*)g,
                                     (__attribute__((address_space(3))) unsigned int*)l, 16, 0, 0);
  }

  for (int n = 0; n < 64; ++n) {
    const int cur = n & 1;
    if (n < 63) {
      const unsigned short* src = ops + (size_t)(n + 1) * OPS_CH;
#pragma unroll
      for (int k = 0; k < 18; ++k) {
        int i = w * 18 + k;
        const unsigned short* g = src + (size_t)i * 512 + lane * 8;
        unsigned short* l = &sOps[cur ^ 1][i * 512];
        __builtin_amdgcn_global_load_lds((const __attribute__((address_space(1))) unsigned int*)g,
                                         (__attribute__((address_space(3))) unsigned int*)l, 16, 0, 0);
      }
      asm volatile("s_waitcnt vmcnt(18)" ::: "memory");
    } else {
      asm volatile("s_waitcnt vmcnt(0)" ::: "memory");
    }
    __builtin_amdgcn_s_barrier();

    const unsigned short* L = &sOps[cur][0];
    const unsigned short* LW = L;
    const unsigned short* LQ = L + 8192;
    const unsigned short* LK = L + 16384;
    const unsigned short* LU = L + 24576;
    const unsigned short* LA = L + 32768;
    const int fo = lane * 8;

    // ---- phase 1: wu = w@S, oo = q@S (per dvb) ----
    f32x16 wu0, oo0, wu1, oo1;
#pragma unroll
    for (int e = 0; e < 16; ++e) { wu0[e] = 0.f; oo0[e] = 0.f; wu1[e] = 0.f; oo1[e] = 0.f; }
#pragma unroll
    for (int st = 0; st < 8; ++st) {
      short8v s00, s01, s10, s11;
      mkfrag(S0[st], s00, s01);
      mkfrag(S1[st], s10, s11);
      short8v wa0 = *(const short8v*)&LW[(st * 2 + 0) * 512 + fo];
      short8v wa1 = *(const short8v*)&LW[(st * 2 + 1) * 512 + fo];
      short8v qa0 = *(const short8v*)&LQ[(st * 2 + 0) * 512 + fo];
      short8v qa1 = *(const short8v*)&LQ[(st * 2 + 1) * 512 + fo];
      wu0 = __builtin_amdgcn_mfma_f32_32x32x16_bf16(wa0, s00, wu0, 0, 0, 0);
      wu0 = __builtin_amdgcn_mfma_f32_32x32x16_bf16(wa1, s01, wu0, 0, 0, 0);
      oo0 = __builtin_amdgcn_mfma_f32_32x32x16_bf16(qa0, s00, oo0, 0, 0, 0);
      oo0 = __builtin_amdgcn_mfma_f32_32x32x16_bf16(qa1, s01, oo0, 0, 0, 0);
      wu1 = __builtin_amdgcn_mfma_f32_32x32x16_bf16(wa0, s10, wu1, 0, 0, 0);
      wu1 = __builtin_amdgcn_mfma_f32_32x32x16_bf16(wa1, s11, wu1, 0, 0, 0);
      oo1 = __builtin_amdgcn_mfma_f32_32x32x16_bf16(qa0, s10, oo1, 0, 0, 0);
      oo1 = __builtin_amdgcn_mfma_f32_32x32x16_bf16(qa1, s11, oo1, 0, 0, 0);
    }

    // ---- phase 2: u_t = u - wu -> B-frags (per dvb) ----
    f32x16 ut0, ut1;
#pragma unroll
    for (int g = 0; g < 4; ++g) {
      uint2 a = *(const uint2*)&LU[((dvb0 + 0) * 4 + g) * 256 + lane * 4];
      uint2 c = *(const uint2*)&LU[((dvb0 + 1) * 4 + g) * 256 + lane * 4];
      ut0[4 * g + 0] = bf2f(a.x & 0xffffu) - wu0[4 * g + 0];
      ut0[4 * g + 1] = bf2f(a.x >> 16)     - wu0[4 * g + 1];
      ut0[4 * g + 2] = bf2f(a.y & 0xffffu) - wu0[4 * g + 2];
      ut0[4 * g + 3] = bf2f(a.y >> 16)     - wu0[4 * g + 3];
      ut1[4 * g + 0] = bf2f(c.x & 0xffffu) - wu1[4 * g + 0];
      ut1[4 * g + 1] = bf2f(c.x >> 16)     - wu1[4 * g + 1];
      ut1[4 * g + 2] = bf2f(c.y & 0xffffu) - wu1[4 * g + 2];
      ut1[4 * g + 3] = bf2f(c.y >> 16)     - wu1[4 * g + 3];
    }
    short8v u0k0, u0k1, u1k0, u1k1;
    mkfrag(ut0, u0k0, u0k1);
    mkfrag(ut1, u1k0, u1k1);

    // ---- phase 3: oo += attn @ u_t ; S += k^T @ u_t ----
    {
      short8v aa0 = *(const short8v*)&LA[0 * 512 + fo];
      short8v aa1 = *(const short8v*)&LA[1 * 512 + fo];
      oo0 = __builtin_amdgcn_mfma_f32_32x32x16_bf16(aa0, u0k0, oo0, 0, 0, 0);
      oo0 = __builtin_amdgcn_mfma_f32_32x32x16_bf16(aa1, u0k1, oo0, 0, 0, 0);
      oo1 = __builtin_amdgcn_mfma_f32_32x32x16_bf16(aa0, u1k0, oo1, 0, 0, 0);
      oo1 = __builtin_amdgcn_mfma_f32_32x32x16_bf16(aa1, u1k1, oo1, 0, 0, 0);
    }
#pragma unroll
    for (int st = 0; st < 8; ++st) {
      short8v ka0 = *(const short8v*)&LK[(st * 2 + 0) * 512 + fo];
      short8v ka1 = *(const short8v*)&LK[(st * 2 + 1) * 512 + fo];
      S0[st] = __builtin_amdgcn_mfma_f32_32x32x16_bf16(ka0, u0k0, S0[st], 0, 0, 0);
      S0[st] = __builtin_amdgcn_mfma_f32_32x32x16_bf16(ka1, u0k1, S0[st], 0, 0, 0);
      S1[st] = __builtin_amdgcn_mfma_f32_32x32x16_bf16(ka0, u1k0, S1[st], 0, 0, 0);
      S1[st] = __builtin_amdgcn_mfma_f32_32x32x16_bf16(ka1, u1k1, S1[st], 0, 0, 0);
    }

    // ---- write delta (fp32) ----
    {
      size_t ob0 = ((size_t)(b * NL + n * 32)) * ND + h * 256 + (dvb0 + 0) * 32 + l31;
      size_t ob1 = ((size_t)(b * NL + n * 32)) * ND + h * 256 + (dvb0 + 1) * 32 + l31;
#pragma unroll
      for (int e = 0; e < 16; ++e) {
        int row = (e & 3) + 8 * (e >> 2) + 4 * lhi;
        g_delta[ob0 + (size_t)row * ND] = oo0[e];
        g_delta[ob1 + (size_t)row * ND] = oo1[e];
      }
    }

    asm volatile("s_waitcnt lgkmcnt(0)" ::: "memory");
    __builtin_amdgcn_s_barrier();
  }
}

// ================= per-branch stats =================
__global__ __launch_bounds__(64) void stats_kernel() {
  int g = blockIdx.x;               // bl*4 + h
  int h = g & 3, bl = g >> 2;
  int lane = threadIdx.x;
  size_t base = (size_t)bl * ND + h * 256 + lane * 4;
#pragma unroll
  for (int br = 0; br < 4; ++br) {
    const float* p = (br == 0) ? g_fs : (br == 1) ? g_fl : (br == 2) ? g_delta : g_v;
    float4 x4 = *(const float4*)&p[base];
    float s = x4.x + x4.y + x4.z + x4.w;
    float s2 = x4.x * x4.x + x4.y * x4.y + x4.z * x4.z + x4.w * x4.w;
    float sa = fabsf(x4.x) + fabsf(x4.y) + fabsf(x4.z) + fabsf(x4.w);
#pragma unroll
    for (int off = 32; off; off >>= 1) {
      s += __shfl_xor(s, off);
      s2 += __shfl_xor(s2, off);
      sa += __shfl_xor(sa, off);
    }
    if (lane == 0) {
      float mean = s * (1.f / 256.f);
      float4 o;
      o.x = mean;
      o.y = s2 * (1.f / 256.f) - mean * mean;
      o.z = sa * (1.f / 256.f);
      o.w = sqrtf(s2);
      *(float4*)&g_stats[(size_t)g * 16 + br * 4] = o;
    }
  }
}

// ================= gate MLP tail + softmax/floor =================
__global__ __launch_bounds__(256) void gate_kernel(const float* __restrict__ W1,
                                                   const float* __restrict__ b1,
                                                   const float* __restrict__ W2,
                                                   const float* __restrict__ b2,
                                                   const float* __restrict__ log_temp,
                                                   const float* __restrict__ base_bias,
                                                   const float* __restrict__ crl) {
  __shared__ float st[4][16];
  __shared__ float red[4][4];
  int bl = blockIdx.x, t = threadIdx.x;
  if (t < 64) (&st[0][0])[t] = g_stats[(size_t)bl * 64 + t];
  __syncthreads();
  const float* W1s = W1 + 1024 * 1024;
  for (int h = 0; h < 4; ++h) {
    float sv[16];
#pragma unroll
    for (int s = 0; s < 16; ++s) sv[s] = st[h][s];
    float a0 = 0.f, a1 = 0.f, a2 = 0.f, a3 = 0.f;
    for (int j = t; j < 1024; j += 256) {
      float val = g_xw1[(size_t)bl * 1024 + j] + b1[j];
#pragma unroll
      for (int s = 0; s < 16; ++s) val += sv[s] * W1s[s * 1024 + j];
      float gg = 0.5f * val * (1.f + erff(val * 0.70710678118654752f));
      float4 w2 = *(const float4*)&W2[j * 4];
      a0 += gg * w2.x; a1 += gg * w2.y; a2 += gg * w2.z; a3 += gg * w2.w;
    }
#pragma unroll
    for (int off = 32; off; off >>= 1) {
      a0 += __shfl_xor(a0, off); a1 += __shfl_xor(a1, off);
      a2 += __shfl_xor(a2, off); a3 += __shfl_xor(a3, off);
    }
    int wv = t >> 6, lane = t & 63;
    if (lane == 0) { red[wv][0] = a0; red[wv][1] = a1; red[wv][2] = a2; red[wv][3] = a3; }
    __syncthreads();
    if (t == 0) {
      float lg[4];
#pragma unroll
      for (int m = 0; m < 4; ++m)
        lg[m] = red[0][m] + red[1][m] + red[2][m] + red[3][m] + b2[m] + base_bias[h * 4 + m];
      float lt = log_temp[h];
      float sp = (lt > 20.f) ? lt : log1pf(expf(lt));
      float inv = 1.f / (sp + 1e-4f);
      float z0 = lg[0] * inv, z1 = lg[1] * inv, z2 = lg[2] * inv, z3 = lg[3] * inv;
      float mx = fmaxf(fmaxf(z0, z1), fmaxf(z2, z3));
      float e0 = expf(z0 - mx), e1 = expf(z1 - mx), e2 = expf(z2 - mx), e3 = expf(z3 - mx);
      float si = 1.f / (e0 + e1 + e2 + e3);
      float p0 = e0 * si, p1 = e1 * si, p2 = e2 * si, p3 = e3 * si;
      p0 = fmaxf(p0, 0.05f); p1 = fmaxf(p1, 0.05f);
      float s2i = 1.f / (p0 + p1 + p2 + p3);
      p0 *= s2i; p1 *= s2i; p2 *= s2i; p3 *= s2i;
      p0 += 0.5f * sigmoidf(crl[h]);   // fold conv-residual into f_short coeff
      float4 pv; pv.x = p0; pv.y = p1; pv.z = p2; pv.w = p3;
      *(float4*)&g_p[((size_t)bl * 4 + h) * 4] = pv;
    }
    __syncthreads();
  }
}

// ================= mix 4 branches + RMSNorm =================
__global__ __launch_bounds__(256) void mix_rms_kernel(const float* __restrict__ rms_w) {
  int bl = blockIdx.x;
  int h = threadIdx.x >> 6, lane = threadIdx.x & 63;
  const float* pp = &g_p[((size_t)bl * 4 + h) * 4];
  float p0 = pp[0], p1 = pp[1], p2 = pp[2], p3 = pp[3];
  size_t base = (size_t)bl * ND + h * 256 + lane * 4;
  float4 a = *(const float4*)&g_fs[base];
  float4 bb = *(const float4*)&g_fl[base];
  float4 c = *(const float4*)&g_delta[base];
  float4 d = *(const float4*)&g_v[base];
  float o0 = p0 * a.x + p1 * bb.x + p2 * c.x + p3 * d.x;
  float o1 = p0 * a.y + p1 * bb.y + p2 * c.y + p3 * d.y;
  float o2 = p0 * a.z + p1 * bb.z + p2 * c.z + p3 * d.z;
  float o3 = p0 * a.w + p1 * bb.w + p2 * c.w + p3 * d.w;
  float s2 = o0 * o0 + o1 * o1 + o2 * o2 + o3 * o3;
#pragma unroll
  for (int off = 32; off; off >>= 1) s2 += __shfl_xor(s2, off);
  float rms = rsqrtf(s2 * (1.f / 256.f) + 1e-5f);
  float4 w4 = *(const float4*)&rms_w[lane * 4];
  float4 o;
  o.x = o0 * rms * w4.x; o.y = o1 * rms * w4.y; o.z = o2 * rms * w4.z; o.w = o3 * rms * w4.w;
  *(float4*)&g_omix[base] = o;
}

extern "C" void kernel_launch(void* const* d_in, const int* in_sizes, int n_in,
                              void* d_out, int out_size, void* d_ws, size_t ws_size,
                              hipStream_t stream) {
  const float* x = (const float*)d_in[0];
  const float* Wq = (const float*)d_in[1];
  const float* Wk = (const float*)d_in[2];
  const float* Wv = (const float*)d_in[3];
  const float* Wb = (const float*)d_in[4];
  const float* cq = (const float*)d_in[5];
  const float* ck = (const float*)d_in[6];
  const float* cv = (const float*)d_in[7];
  const float* firl = (const float*)d_in[8];
  const float* firs = (const float*)d_in[9];
  const float* W1 = (const float*)d_in[10];
  const float* b1 = (const float*)d_in[11];
  const float* W2 = (const float*)d_in[12];
  const float* b2 = (const float*)d_in[13];
  const float* ltp = (const float*)d_in[14];
  const float* bbs = (const float*)d_in[15];
  const float* crl = (const float*)d_in[16];
  const float* rw = (const float*)d_in[17];
  const float* Wo = (const float*)d_in[18];
  float* out = (float*)d_out;

  dim3 gemm_grid(8, 32), blk(256);
  sgemm_kernel<<<gemm_grid, blk, 0, stream>>>(x, Wq, nullptr, 0);
  sgemm_kernel<<<gemm_grid, blk, 0, stream>>>(x, Wk, nullptr, 1);
  sgemm_kernel<<<gemm_grid, blk, 0, stream>>>(x, Wv, nullptr, 2);
  conv_silu_kernel<<<BLDSZ / 256, blk, 0, stream>>>(cq, 0);
  conv_silu_kernel<<<BLDSZ / 256, blk, 0, stream>>>(ck, 1);
  conv_silu_kernel<<<BLDSZ / 256, blk, 0, stream>>>(cv, 2);
  beta_kernel<<<NBL, blk, 0, stream>>>(x, Wb);
  sgemm_kernel<<<gemm_grid, blk, 0, stream>>>(x, W1, nullptr, 3);  // x @ W1[:1024,:]
  delta_prep_kernel<<<NB * NH * NCHK, blk, 0, stream>>>();
  delta_scan_mfma<<<8, dim3(256), 0, stream>>>();
  fir_short_kernel<<<BLDSZ / 256, blk, 0, stream>>>(firs);
  fir_long_kernel<<<512, blk, 0, stream>>>(firl);
  stats_kernel<<<NBL * NH, dim3(64), 0, stream>>>();
  gate_kernel<<<NBL, blk, 0, stream>>>(W1, b1, W2, b2, ltp, bbs, crl);
  mix_rms_kernel<<<NBL, blk, 0, stream>>>(rw);
  sgemm_kernel<<<gemm_grid, blk, 0, stream>>>(nullptr, Wo, out, 4);
}

// Round 5
// 825.787 us; speedup vs baseline: 2.1278x; 2.1278x over previous
//
#include <hip/hip_runtime.h>
#include <math.h>

// Problem constants
constexpr int NB = 2, NL = 2048, ND = 1024, NH = 4;
constexpr int NCHK = 64;            // L / 32
constexpr int NBL = NB * NL;        // 4096
#define BLDSZ (NB * NL * ND)        // 4194304

// per-chunk packed operand file (shorts): [W 8192 | Q 8192 | Kt 8192 | Ut 8192 | At 1024 | pad]
constexpr int OPS_CH = 36864;       // shorts = 72 KB

// ---- static device scratch ----
__device__ float g_qlin[BLDSZ];
__device__ float g_klin[BLDSZ];
__device__ float g_vlin[BLDSZ];
__device__ float g_q[BLDSZ];      // post conv+silu (fp32, prep input)
__device__ float g_k[BLDSZ];
__device__ float g_v[BLDSZ];
__device__ float g_delta[BLDSZ];  // (B,L,H,DV)
__device__ float g_fs[BLDSZ];
__device__ float g_fl[BLDSZ];
__device__ float g_xw1[BLDSZ];    // x @ W1[:1024,:]
__device__ float g_beta[NBL * NH];
__device__ float g_stats[NBL * NH * 16];
__device__ float g_p[NBL * NH * 4];
__device__ unsigned short g_ops[(size_t)8 * 64 * OPS_CH];  // 37.7 MB
__device__ unsigned short g_xb[BLDSZ];                      // x bf16
__device__ unsigned short g_omixb[BLDSZ];                   // mixed output bf16
__device__ unsigned short g_btw[5 * 1024 * 1024];           // 5 weights, [n][k] bf16

__device__ __forceinline__ float sigmoidf(float x) { return 1.f / (1.f + expf(-x)); }

__device__ __forceinline__ unsigned short f2bf(float f) {
  union { float f; unsigned int u; } v; v.f = f;
  unsigned int r = v.u + 0x7FFFu + ((v.u >> 16) & 1u);   // RNE
  return (unsigned short)(r >> 16);
}
__device__ __forceinline__ float bf2f(unsigned int bits16) {
  union { unsigned int u; float f; } v; v.u = bits16 << 16; return v.f;
}
__device__ __forceinline__ unsigned int packbf(float a, float b) {
  return (unsigned int)f2bf(a) | ((unsigned int)f2bf(b) << 16);
}

typedef __attribute__((ext_vector_type(8))) short short8v;   // 8 bf16 (4 VGPR)
typedef __attribute__((ext_vector_type(16))) float f32x16;   // MFMA 32x32 accum

__device__ __forceinline__ unsigned int cvtpk(float lo, float hi) {
  unsigned int r;
  asm("v_cvt_pk_bf16_f32 %0, %1, %2" : "=v"(r) : "v"(lo), "v"(hi));
  return r;
}

// C-layout f32x16 (col=l31, row=(e&3)+8*(e>>2)+4*lhi) -> two K-slice B-frags
__device__ __forceinline__ void mkfrag(const f32x16 v, short8v& fb0, short8v& fb1) {
  unsigned int P0 = cvtpk(v[0], v[1]),   P1 = cvtpk(v[2], v[3]);
  unsigned int P2 = cvtpk(v[4], v[5]),   P3 = cvtpk(v[6], v[7]);
  unsigned int P4 = cvtpk(v[8], v[9]),   P5 = cvtpk(v[10], v[11]);
  unsigned int P6 = cvtpk(v[12], v[13]), P7 = cvtpk(v[14], v[15]);
  asm("v_permlane32_swap_b32 %0, %1" : "+v"(P0), "+v"(P2));
  asm("v_permlane32_swap_b32 %0, %1" : "+v"(P1), "+v"(P3));
  asm("v_permlane32_swap_b32 %0, %1" : "+v"(P4), "+v"(P6));
  asm("v_permlane32_swap_b32 %0, %1" : "+v"(P5), "+v"(P7));
  unsigned int f0[4] = {P0, P1, P2, P3}, f1[4] = {P4, P5, P6, P7};
  fb0 = *(short8v*)f0; fb1 = *(short8v*)f1;
}

// ================= pack x -> bf16 =================
__global__ __launch_bounds__(256) void packx_kernel(const float* __restrict__ x) {
  int i8 = blockIdx.x * 256 + threadIdx.x;
  const float* p = x + (size_t)i8 * 8;
  float4 a = *(const float4*)p;
  float4 b = *(const float4*)(p + 4);
  uint4 v;
  v.x = packbf(a.x, a.y); v.y = packbf(a.z, a.w);
  v.z = packbf(b.x, b.y); v.w = packbf(b.z, b.w);
  *(uint4*)&g_xb[(size_t)i8 * 8] = v;
}

// ================= pack weight 1024x1024 fp32 [k][n] -> bf16 [n][k] =================
__global__ __launch_bounds__(256) void packw_kernel(const float* __restrict__ W, int sel) {
  __shared__ float tile[64][65];
  int bx = blockIdx.x & 15, by = blockIdx.x >> 4;  // n-tile, k-tile
  int n0 = bx * 64, k0 = by * 64;
  int t = threadIdx.x;
#pragma unroll
  for (int i = 0; i < 4; ++i) {
    int id = t + i * 256;
    int r = id >> 4, c4 = (id & 15) * 4;
    float4 v = *(const float4*)&W[(size_t)(k0 + r) * 1024 + n0 + c4];
    tile[r][c4 + 0] = v.x; tile[r][c4 + 1] = v.y; tile[r][c4 + 2] = v.z; tile[r][c4 + 3] = v.w;
  }
  __syncthreads();
  unsigned int* out = (unsigned int*)g_btw + (size_t)sel * 524288;
#pragma unroll
  for (int i = 0; i < 8; ++i) {
    int id = t + i * 256;
    int nn = id >> 5, ku = id & 31;
    out[(size_t)(n0 + nn) * 512 + (k0 >> 1) + ku] = packbf(tile[2 * ku][nn], tile[2 * ku + 1][nn]);
  }
}

// ================= bf16 MFMA GEMM: C[4096,1024] = A @ Bt^T =================
// A bf16 row-major [m][k]; Bt bf16 [n][k]. 128x128 tile, 4 waves, 2x2 32x32 frags/wave.
__global__ __launch_bounds__(256) void hgemm_kernel(int sel, float* __restrict__ Cext) {
  __shared__ unsigned short As[4096];   // 128 rows x 32 k, 16B-chunk XOR swizzle
  __shared__ unsigned short Bs[4096];
  const unsigned short* A = (sel == 4) ? g_omixb : g_xb;
  const unsigned short* Bt = g_btw + (size_t)sel * 1024 * 1024;
  float* C = (sel == 0) ? g_qlin : (sel == 1) ? g_klin : (sel == 2) ? g_vlin
           : (sel == 3) ? g_xw1 : Cext;
  const int t = threadIdx.x;
  const int bx = blockIdx.x & 7, by = blockIdx.x >> 3;
  const int m0 = by * 128, n0 = bx * 128;
  const int w = t >> 6, lane = t & 63, l31 = lane & 31, lhi = lane >> 5;
  const int wm = (w & 1) * 64, wn = (w >> 1) * 64;
  f32x16 acc[2][2];
#pragma unroll
  for (int mt = 0; mt < 2; ++mt)
#pragma unroll
    for (int nt = 0; nt < 2; ++nt)
#pragma unroll
      for (int e = 0; e < 16; ++e) acc[mt][nt][e] = 0.f;

  for (int k0 = 0; k0 < 1024; k0 += 32) {
#pragma unroll
    for (int i = 0; i < 2; ++i) {
      int c = t + i * 256;
      int row = c >> 2, kb = c & 3;
      int sw = (row * 4 + kb) ^ (row & 7);
      *(uint4*)&As[sw * 8] = *(const uint4*)&A[(size_t)(m0 + row) * 1024 + k0 + kb * 8];
      *(uint4*)&Bs[sw * 8] = *(const uint4*)&Bt[(size_t)(n0 + row) * 1024 + k0 + kb * 8];
    }
    __syncthreads();
#pragma unroll
    for (int ksl = 0; ksl < 2; ++ksl) {
      int kb = ksl * 2 + lhi;
      short8v af[2], bf[2];
#pragma unroll
      for (int mt = 0; mt < 2; ++mt) {
        int row = wm + mt * 32 + l31;
        af[mt] = *(const short8v*)&As[((row * 4 + kb) ^ (row & 7)) * 8];
      }
#pragma unroll
      for (int nt = 0; nt < 2; ++nt) {
        int row = wn + nt * 32 + l31;
        bf[nt] = *(const short8v*)&Bs[((row * 4 + kb) ^ (row & 7)) * 8];
      }
#pragma unroll
      for (int mt = 0; mt < 2; ++mt)
#pragma unroll
        for (int nt = 0; nt < 2; ++nt)
          acc[mt][nt] = __builtin_amdgcn_mfma_f32_32x32x16_bf16(af[mt], bf[nt], acc[mt][nt], 0, 0, 0);
    }
    __syncthreads();
  }
#pragma unroll
  for (int mt = 0; mt < 2; ++mt)
#pragma unroll
    for (int nt = 0; nt < 2; ++nt) {
      int col = n0 + wn + nt * 32 + l31;
#pragma unroll
      for (int e = 0; e < 16; ++e) {
        int row = m0 + wm + mt * 32 + (e & 3) + 8 * (e >> 2) + 4 * lhi;
        C[(size_t)row * 1024 + col] = acc[mt][nt][e];
      }
    }
}

// ================= causal depthwise conv (K=4) + SiLU =================
__global__ __launch_bounds__(256) void conv_silu_kernel(const float* __restrict__ cw, int sel) {
  const float* in = (sel == 0) ? g_qlin : (sel == 1) ? g_klin : g_vlin;
  float* out = (sel == 0) ? g_q : (sel == 1) ? g_k : g_v;
  int idx = blockIdx.x * 256 + threadIdx.x;
  int c = idx & (ND - 1);
  int bl = idx >> 10;
  int l = bl & (NL - 1);
  float w0 = cw[c * 4 + 0], w1 = cw[c * 4 + 1], w2 = cw[c * 4 + 2], w3 = cw[c * 4 + 3];
  float acc = w3 * in[(size_t)bl * ND + c];
  if (l >= 1) acc += w2 * in[(size_t)(bl - 1) * ND + c];
  if (l >= 2) acc += w1 * in[(size_t)(bl - 2) * ND + c];
  if (l >= 3) acc += w0 * in[(size_t)(bl - 3) * ND + c];
  out[idx] = acc * sigmoidf(acc);
}

// ================= beta = sigmoid(x @ Wb) =================
__global__ __launch_bounds__(256) void beta_kernel(const float* __restrict__ x,
                                                   const float* __restrict__ Wb) {
  int bl = blockIdx.x;
  int h = threadIdx.x >> 6, lane = threadIdx.x & 63;
  const float* xr = x + (size_t)bl * ND;
  float acc = 0.f;
  for (int d = lane; d < ND; d += 64) acc += xr[d] * Wb[d * 4 + h];
#pragma unroll
  for (int off = 32; off; off >>= 1) acc += __shfl_xor(acc, off);
  if (lane == 0) g_beta[bl * 4 + h] = sigmoidf(acc);
}

// ================= FIR short (K=5) =================
__global__ __launch_bounds__(256) void fir_short_kernel(const float* __restrict__ filt) {
  int idx = blockIdx.x * 256 + threadIdx.x;
  int c = idx & (ND - 1);
  int bl = idx >> 10;
  int l = bl & (NL - 1);
  const float* fp = filt + c * 5;
  float acc = 0.f;
#pragma unroll
  for (int tap = 0; tap < 5; ++tap) {
    int ls = l + tap - 4;
    if (ls >= 0) acc += fp[tap] * g_v[(size_t)(bl + tap - 4) * ND + c];
  }
  g_fs[idx] = acc;
}

// ================= FIR long (K=64) — register filter + unrolled scatter =================
__global__ __launch_bounds__(256) void fir_long_kernel(const float* __restrict__ filt) {
  int blk = blockIdx.x;
  int cbk = blk & 3, lb = (blk >> 2) & 63, b = blk >> 8;
  int t = threadIdx.x;
  int c = cbk * 256 + t;
  float ff[64];
#pragma unroll
  for (int i = 0; i < 16; ++i)
    *(float4*)&ff[i * 4] = *(const float4*)&filt[(size_t)c * 64 + i * 4];
  float acc[32];
#pragma unroll
  for (int i = 0; i < 32; ++i) acc[i] = 0.f;
  const float* vb = g_v + (size_t)b * NL * ND + c;
  const int l0 = lb * 32;
#pragma unroll
  for (int d = 0; d < 95; ++d) {
    int lr = l0 - 63 + d;
    float vv = (lr >= 0) ? vb[(size_t)lr * ND] : 0.f;
    const int lo = (d > 63) ? (d - 63) : 0;
    const int hi = (d < 31) ? d : 31;
#pragma unroll
    for (int li = lo; li <= hi; ++li) acc[li] += ff[d - li] * vv;
  }
  float* ob = g_fl + ((size_t)(b * NL + l0)) * ND + c;
#pragma unroll
  for (int li = 0; li < 32; ++li) ob[(size_t)li * ND] = acc[li];
}

// ================= delta-rule chunk prep (emits frag-major g_ops) =================
__global__ __launch_bounds__(256) void delta_prep_kernel() {
  __shared__ float X[32][260];
  __shared__ float Y[32][260];
  __shared__ float Am[32][33];
  __shared__ float Tm[32][33];
  __shared__ float bet[32];
  int blk = blockIdx.x;                  // cblk = (b*4+h)*64 + n
  int n = blk & 63, h = (blk >> 6) & 3, b = blk >> 8;
  int t = threadIdx.x;
  size_t rowbase = (size_t)(b * NL + n * 32);
  size_t obase = (size_t)blk * OPS_CH;
  const int st_ = t >> 5, j_ = (t >> 4) & 1, lh_ = (t >> 3) & 1, e_ = t & 7;
  const int l31_ = t & 31;

#pragma unroll
  for (int i = 0; i < 8; ++i) {
    int j = t + i * 256;
    int r = j >> 6, d4 = (j & 63) << 2;
    size_t gi = (rowbase + r) * ND + h * 256 + d4;
    *(float4*)&X[r][d4] = *(const float4*)&g_q[gi];
    *(float4*)&Y[r][d4] = *(const float4*)&g_k[gi];
  }
  if (t < 32) bet[t] = g_beta[(rowbase + t) * 4 + h];
  __syncthreads();

  {
    int wv = t >> 6, lane = t & 63;
    int r = wv * 8 + (lane >> 3), sub = lane & 7;
    float sq = 0.f, sk = 0.f;
#pragma unroll
    for (int m4 = 0; m4 < 8; ++m4) {
      float4 a = *(const float4*)&X[r][sub * 32 + m4 * 4];
      float4 bb = *(const float4*)&Y[r][sub * 32 + m4 * 4];
      sq += a.x * a.x + a.y * a.y + a.z * a.z + a.w * a.w;
      sk += bb.x * bb.x + bb.y * bb.y + bb.z * bb.z + bb.w * bb.w;
    }
    sq += __shfl_xor(sq, 1); sq += __shfl_xor(sq, 2); sq += __shfl_xor(sq, 4);
    sk += __shfl_xor(sk, 1); sk += __shfl_xor(sk, 2); sk += __shfl_xor(sk, 4);
    float rq = rsqrtf(sq + 1e-6f), rk = rsqrtf(sk + 1e-6f);
#pragma unroll
    for (int m4 = 0; m4 < 8; ++m4) {
      float4 a = *(const float4*)&X[r][sub * 32 + m4 * 4];
      a.x *= rq; a.y *= rq; a.z *= rq; a.w *= rq;
      *(float4*)&X[r][sub * 32 + m4 * 4] = a;
      float4 bb = *(const float4*)&Y[r][sub * 32 + m4 * 4];
      bb.x *= rk; bb.y *= rk; bb.z *= rk; bb.w *= rk;
      *(float4*)&Y[r][sub * 32 + m4 * 4] = bb;
    }
  }
  __syncthreads();

  // attn = incl_lower(qn kn^T) -> At region
#pragma unroll
  for (int i = 0; i < 4; ++i) {
    int pr = t + i * 256;
    int r = pr >> 5, s = pr & 31;
    float acc = 0.f;
    if (s <= r) {
#pragma unroll 16
      for (int d4 = 0; d4 < 64; ++d4) {
        float4 a = *(const float4*)&X[r][d4 * 4];
        float4 bb = *(const float4*)&Y[s][d4 * 4];
        acc += a.x * bb.x + a.y * bb.y + a.z * bb.z + a.w * bb.w;
      }
    }
    g_ops[obase + 32768 + (((s >> 4) * 64) + ((s >> 3) & 1) * 32 + r) * 8 + (s & 7)] = f2bf(acc);
  }

  // qn -> Q region; kn -> Kt region
  {
    size_t qb = obase + 8192 + (size_t)(((st_ * 2 + j_) * 64) + lh_ * 32) * 8 + e_;
#pragma unroll 8
    for (int r = 0; r < 32; ++r)
      g_ops[qb + r * 8] = f2bf(X[r][t]);
#pragma unroll
    for (int j = 0; j < 2; ++j)
#pragma unroll
      for (int lh = 0; lh < 2; ++lh) {
        int kr0 = j * 16 + lh * 8;
        uint4 v;
        v.x = packbf(Y[kr0 + 0][t], Y[kr0 + 1][t]);
        v.y = packbf(Y[kr0 + 2][t], Y[kr0 + 3][t]);
        v.z = packbf(Y[kr0 + 4][t], Y[kr0 + 5][t]);
        v.w = packbf(Y[kr0 + 6][t], Y[kr0 + 7][t]);
        *(uint4*)&g_ops[obase + 16384 + (size_t)(((st_ * 2 + j) * 64) + lh * 32 + l31_) * 8] = v;
      }
  }
  __syncthreads();

  // X <- k_beta
#pragma unroll
  for (int i = 0; i < 8; ++i) {
    int j = t + i * 256;
    int r = j >> 6, d4 = (j & 63) << 2;
    float be = bet[r];
    float4 bb = *(const float4*)&Y[r][d4];
    bb.x *= be; bb.y *= be; bb.z *= be; bb.w *= be;
    *(float4*)&X[r][d4] = bb;
  }
  __syncthreads();

  // A = strict_lower(kb kn^T)
#pragma unroll
  for (int i = 0; i < 4; ++i) {
    int pr = t + i * 256;
    int r = pr >> 5, s = pr & 31;
    float acc = 0.f;
    if (s < r) {
#pragma unroll 16
      for (int d4 = 0; d4 < 64; ++d4) {
        float4 a = *(const float4*)&X[r][d4 * 4];
        float4 bb = *(const float4*)&Y[s][d4 * 4];
        acc += a.x * bb.x + a.y * bb.y + a.z * bb.z + a.w * bb.w;
      }
    }
    Am[r][s] = acc;
  }
  __syncthreads();

  if (t < 32) {
    int j = t;
    for (int i = 0; i < 32; ++i) {
      float a = (i == j) ? 1.f : 0.f;
      for (int m = j; m < i; ++m) a -= Am[i][m] * Tm[m][j];
      Tm[i][j] = a;
    }
  }
  __syncthreads();

  // w = T @ kb -> W region
  {
    float acc[32];
#pragma unroll
    for (int r = 0; r < 32; ++r) acc[r] = 0.f;
#pragma unroll
    for (int m = 0; m < 32; ++m) {
      float xv = X[m][t];
#pragma unroll
      for (int r = m; r < 32; ++r) acc[r] += Tm[r][m] * xv;
    }
    size_t wb = obase + (size_t)(((st_ * 2 + j_) * 64) + lh_ * 32) * 8 + e_;
#pragma unroll 8
    for (int r = 0; r < 32; ++r)
      g_ops[wb + r * 8] = f2bf(acc[r]);
  }
  // Y <- v*beta
#pragma unroll
  for (int i = 0; i < 8; ++i) {
    int j = t + i * 256;
    int r = j >> 6, d4 = (j & 63) << 2;
    size_t gi = (rowbase + r) * ND + h * 256 + d4;
    float be = bet[r];
    float4 vv = *(const float4*)&g_v[gi];
    vv.x *= be; vv.y *= be; vv.z *= be; vv.w *= be;
    *(float4*)&Y[r][d4] = vv;
  }
  __syncthreads();

  // u = T @ vb -> Ut region
  {
    float acc[32];
#pragma unroll
    for (int r = 0; r < 32; ++r) acc[r] = 0.f;
#pragma unroll
    for (int m = 0; m < 32; ++m) {
      float yv = Y[m][t];
#pragma unroll
      for (int r = m; r < 32; ++r) acc[r] += Tm[r][m] * yv;
    }
    int q = t >> 5;
#pragma unroll
    for (int g = 0; g < 4; ++g)
#pragma unroll
      for (int lh = 0; lh < 2; ++lh) {
        int kr0 = 8 * g + 4 * lh;
        uint2 v;
        v.x = packbf(acc[kr0 + 0], acc[kr0 + 1]);
        v.y = packbf(acc[kr0 + 2], acc[kr0 + 3]);
        *(uint2*)&g_ops[obase + 24576 + (size_t)(((q * 4 + g) * 64) + lh * 32 + l31_) * 4] = v;
      }
  }
}

// ================= delta-rule scan — barrier-free, 8 waves/block (1 block per chain) =================
// Wave w = dv-slice (32 cols). S slice in 8 f32x16 accumulators. All loads 16B/lane frag-major.
__global__ __launch_bounds__(512, 2) void delta_scan_mfma() {
  const int bh = blockIdx.x;
  const int b = bh >> 2, h = bh & 3;
  const int t = threadIdx.x;
  const int w = t >> 6;
  const int lane = t & 63, l31 = lane & 31, lhi = lane >> 5;

  f32x16 Sacc[8];
#pragma unroll
  for (int st = 0; st < 8; ++st)
#pragma unroll
    for (int e = 0; e < 16; ++e) Sacc[st][e] = 0.f;

  const unsigned short* ops = g_ops + (size_t)bh * 64 * OPS_CH;
  const int fo = lane * 8;

  for (int n = 0; n < 64; ++n) {
    const unsigned short* L = ops + (size_t)n * OPS_CH;
    f32x16 wuA, wuB, ooA, ooB;
#pragma unroll
    for (int e = 0; e < 16; ++e) { wuA[e] = 0.f; wuB[e] = 0.f; ooA[e] = 0.f; ooB[e] = 0.f; }

    // ---- phase 1: wu = w@S, oo = q@S ----
#pragma unroll
    for (int st = 0; st < 8; ++st) {
      short8v s0, s1;
      mkfrag(Sacc[st], s0, s1);
      short8v wa0 = *(const short8v*)&L[(st * 2 + 0) * 512 + fo];
      short8v wa1 = *(const short8v*)&L[(st * 2 + 1) * 512 + fo];
      short8v qa0 = *(const short8v*)&L[8192 + (st * 2 + 0) * 512 + fo];
      short8v qa1 = *(const short8v*)&L[8192 + (st * 2 + 1) * 512 + fo];
      wuA = __builtin_amdgcn_mfma_f32_32x32x16_bf16(wa0, s0, wuA, 0, 0, 0);
      wuB = __builtin_amdgcn_mfma_f32_32x32x16_bf16(wa1, s1, wuB, 0, 0, 0);
      ooA = __builtin_amdgcn_mfma_f32_32x32x16_bf16(qa0, s0, ooA, 0, 0, 0);
      ooB = __builtin_amdgcn_mfma_f32_32x32x16_bf16(qa1, s1, ooB, 0, 0, 0);
    }

    // ---- phase 2: u_t = u - wu -> B-frags ----
    f32x16 ut;
#pragma unroll
    for (int g = 0; g < 4; ++g) {
      uint2 uu = *(const uint2*)&L[24576 + (size_t)(((w * 4 + g) * 64) + lhi * 32 + l31) * 4];
      ut[4 * g + 0] = bf2f(uu.x & 0xffffu) - wuA[4 * g + 0] - wuB[4 * g + 0];
      ut[4 * g + 1] = bf2f(uu.x >> 16)     - wuA[4 * g + 1] - wuB[4 * g + 1];
      ut[4 * g + 2] = bf2f(uu.y & 0xffffu) - wuA[4 * g + 2] - wuB[4 * g + 2];
      ut[4 * g + 3] = bf2f(uu.y >> 16)     - wuA[4 * g + 3] - wuB[4 * g + 3];
    }
    short8v u0, u1;
    mkfrag(ut, u0, u1);

    // ---- phase 3: oo += attn @ u_t ; S += k^T @ u_t ----
    {
      short8v aa0 = *(const short8v*)&L[32768 + 0 * 512 + fo];
      short8v aa1 = *(const short8v*)&L[32768 + 1 * 512 + fo];
      ooA = __builtin_amdgcn_mfma_f32_32x32x16_bf16(aa0, u0, ooA, 0, 0, 0);
      ooB = __builtin_amdgcn_mfma_f32_32x32x16_bf16(aa1, u1, ooB, 0, 0, 0);
    }
#pragma unroll
    for (int st = 0; st < 8; ++st) {
      short8v ka0 = *(const short8v*)&L[16384 + (st * 2 + 0) * 512 + fo];
      short8v ka1 = *(const short8v*)&L[16384 + (st * 2 + 1) * 512 + fo];
      Sacc[st] = __builtin_amdgcn_mfma_f32_32x32x16_bf16(ka0, u0, Sacc[st], 0, 0, 0);
      Sacc[st] = __builtin_amdgcn_mfma_f32_32x32x16_bf16(ka1, u1, Sacc[st], 0, 0, 0);
    }

    // ---- write delta (fp32) ----
    size_t ob = ((size_t)(b * NL + n * 32)) * ND + h * 256 + w * 32 + l31;
#pragma unroll
    for (int e = 0; e < 16; ++e) {
      int row = (e & 3) + 8 * (e >> 2) + 4 * lhi;
      g_delta[ob + (size_t)row * ND] = ooA[e] + ooB[e];
    }
  }
}

// ================= per-branch stats =================
__global__ __launch_bounds__(64) void stats_kernel() {
  int g = blockIdx.x;               // bl*4 + h
  int h = g & 3, bl = g >> 2;
  int lane = threadIdx.x;
  size_t base = (size_t)bl * ND + h * 256 + lane * 4;
#pragma unroll
  for (int br = 0; br < 4; ++br) {
    const float* p = (br == 0) ? g_fs : (br == 1) ? g_fl : (br == 2) ? g_delta : g_v;
    float4 x4 = *(const float4*)&p[base];
    float s = x4.x + x4.y + x4.z + x4.w;
    float s2 = x4.x * x4.x + x4.y * x4.y + x4.z * x4.z + x4.w * x4.w;
    float sa = fabsf(x4.x) + fabsf(x4.y) + fabsf(x4.z) + fabsf(x4.w);
#pragma unroll
    for (int off = 32; off; off >>= 1) {
      s += __shfl_xor(s, off);
      s2 += __shfl_xor(s2, off);
      sa += __shfl_xor(sa, off);
    }
    if (lane == 0) {
      float mean = s * (1.f / 256.f);
      float4 o;
      o.x = mean;
      o.y = s2 * (1.f / 256.f) - mean * mean;
      o.z = sa * (1.f / 256.f);
      o.w = sqrtf(s2);
      *(float4*)&g_stats[(size_t)g * 16 + br * 4] = o;
    }
  }
}

// ================= gate MLP tail + softmax/floor =================
__global__ __launch_bounds__(256) void gate_kernel(const float* __restrict__ W1,
                                                   const float* __restrict__ b1,
                                                   const float* __restrict__ W2,
                                                   const float* __restrict__ b2,
                                                   const float* __restrict__ log_temp,
                                                   const float* __restrict__ base_bias,
                                                   const float* __restrict__ crl) {
  __shared__ float st[4][16];
  __shared__ float red[4][4];
  int bl = blockIdx.x, t = threadIdx.x;
  if (t < 64) (&st[0][0])[t] = g_stats[(size_t)bl * 64 + t];
  __syncthreads();
  const float* W1s = W1 + 1024 * 1024;
  for (int h = 0; h < 4; ++h) {
    float sv[16];
#pragma unroll
    for (int s = 0; s < 16; ++s) sv[s] = st[h][s];
    float a0 = 0.f, a1 = 0.f, a2 = 0.f, a3 = 0.f;
    for (int j = t; j < 1024; j += 256) {
      float val = g_xw1[(size_t)bl * 1024 + j] + b1[j];
#pragma unroll
      for (int s = 0; s < 16; ++s) val += sv[s] * W1s[s * 1024 + j];
      float gg = 0.5f * val * (1.f + erff(val * 0.70710678118654752f));
      float4 w2 = *(const float4*)&W2[j * 4];
      a0 += gg * w2.x; a1 += gg * w2.y; a2 += gg * w2.z; a3 += gg * w2.w;
    }
#pragma unroll
    for (int off = 32; off; off >>= 1) {
      a0 += __shfl_xor(a0, off); a1 += __shfl_xor(a1, off);
      a2 += __shfl_xor(a2, off); a3 += __shfl_xor(a3, off);
    }
    int wv = t >> 6, lane = t & 63;
    if (lane == 0) { red[wv][0] = a0; red[wv][1] = a1; red[wv][2] = a2; red[wv][3] = a3; }
    __syncthreads();
    if (t == 0) {
      float lg[4];
#pragma unroll
      for (int m = 0; m < 4; ++m)
        lg[m] = red[0][m] + red[1][m] + red[2][m] + red[3][m] + b2[m] + base_bias[h * 4 + m];
      float lt = log_temp[h];
      float sp = (lt > 20.f) ? lt : log1pf(expf(lt));
      float inv = 1.f / (sp + 1e-4f);
      float z0 = lg[0] * inv, z1 = lg[1] * inv, z2 = lg[2] * inv, z3 = lg[3] * inv;
      float mx = fmaxf(fmaxf(z0, z1), fmaxf(z2, z3));
      float e0 = expf(z0 - mx), e1 = expf(z1 - mx), e2 = expf(z2 - mx), e3 = expf(z3 - mx);
      float si = 1.f / (e0 + e1 + e2 + e3);
      float p0 = e0 * si, p1 = e1 * si, p2 = e2 * si, p3 = e3 * si;
      p0 = fmaxf(p0, 0.05f); p1 = fmaxf(p1, 0.05f);
      float s2i = 1.f / (p0 + p1 + p2 + p3);
      p0 *= s2i; p1 *= s2i; p2 *= s2i; p3 *= s2i;
      p0 += 0.5f * sigmoidf(crl[h]);   // fold conv-residual into f_short coeff
      float4 pv; pv.x = p0; pv.y = p1; pv.z = p2; pv.w = p3;
      *(float4*)&g_p[((size_t)bl * 4 + h) * 4] = pv;
    }
    __syncthreads();
  }
}

// ================= mix 4 branches + RMSNorm -> bf16 =================
__global__ __launch_bounds__(256) void mix_rms_kernel(const float* __restrict__ rms_w) {
  int bl = blockIdx.x;
  int h = threadIdx.x >> 6, lane = threadIdx.x & 63;
  const float* pp = &g_p[((size_t)bl * 4 + h) * 4];
  float p0 = pp[0], p1 = pp[1], p2 = pp[2], p3 = pp[3];
  size_t base = (size_t)bl * ND + h * 256 + lane * 4;
  float4 a = *(const float4*)&g_fs[base];
  float4 bb = *(const float4*)&g_fl[base];
  float4 c = *(const float4*)&g_delta[base];
  float4 d = *(const float4*)&g_v[base];
  float o0 = p0 * a.x + p1 * bb.x + p2 * c.x + p3 * d.x;
  float o1 = p0 * a.y + p1 * bb.y + p2 * c.y + p3 * d.y;
  float o2 = p0 * a.z + p1 * bb.z + p2 * c.z + p3 * d.z;
  float o3 = p0 * a.w + p1 * bb.w + p2 * c.w + p3 * d.w;
  float s2 = o0 * o0 + o1 * o1 + o2 * o2 + o3 * o3;
#pragma unroll
  for (int off = 32; off; off >>= 1) s2 += __shfl_xor(s2, off);
  float rms = rsqrtf(s2 * (1.f / 256.f) + 1e-5f);
  float4 w4 = *(const float4*)&rms_w[lane * 4];
  uint2 pw;
  pw.x = packbf(o0 * rms * w4.x, o1 * rms * w4.y);
  pw.y = packbf(o2 * rms * w4.z, o3 * rms * w4.w);
  *(uint2*)&g_omixb[base] = pw;
}

extern "C" void kernel_launch(void* const* d_in, const int* in_sizes, int n_in,
                              void* d_out, int out_size, void* d_ws, size_t ws_size,
                              hipStream_t stream) {
  const float* x = (const float*)d_in[0];
  const float* Wq = (const float*)d_in[1];
  const float* Wk = (const float*)d_in[2];
  const float* Wv = (const float*)d_in[3];
  const float* Wb = (const float*)d_in[4];
  const float* cq = (const float*)d_in[5];
  const float* ck = (const float*)d_in[6];
  const float* cv = (const float*)d_in[7];
  const float* firl = (const float*)d_in[8];
  const float* firs = (const float*)d_in[9];
  const float* W1 = (const float*)d_in[10];
  const float* b1 = (const float*)d_in[11];
  const float* W2 = (const float*)d_in[12];
  const float* b2 = (const float*)d_in[13];
  const float* ltp = (const float*)d_in[14];
  const float* bbs = (const float*)d_in[15];
  const float* crl = (const float*)d_in[16];
  const float* rw = (const float*)d_in[17];
  const float* rms = (const float*)d_in[17];
  const float* Wo = (const float*)d_in[18];
  float* out = (float*)d_out;
  (void)rms;

  dim3 blk(256);
  packx_kernel<<<2048, blk, 0, stream>>>(x);
  packw_kernel<<<256, blk, 0, stream>>>(Wq, 0);
  packw_kernel<<<256, blk, 0, stream>>>(Wk, 1);
  packw_kernel<<<256, blk, 0, stream>>>(Wv, 2);
  packw_kernel<<<256, blk, 0, stream>>>(W1, 3);
  packw_kernel<<<256, blk, 0, stream>>>(Wo, 4);
  hgemm_kernel<<<256, blk, 0, stream>>>(0, nullptr);
  hgemm_kernel<<<256, blk, 0, stream>>>(1, nullptr);
  hgemm_kernel<<<256, blk, 0, stream>>>(2, nullptr);
  hgemm_kernel<<<256, blk, 0, stream>>>(3, nullptr);
  conv_silu_kernel<<<BLDSZ / 256, blk, 0, stream>>>(cq, 0);
  conv_silu_kernel<<<BLDSZ / 256, blk, 0, stream>>>(ck, 1);
  conv_silu_kernel<<<BLDSZ / 256, blk, 0, stream>>>(cv, 2);
  beta_kernel<<<NBL, blk, 0, stream>>>(x, Wb);
  delta_prep_kernel<<<NB * NH * NCHK, blk, 0, stream>>>();
  delta_scan_mfma<<<8, dim3(512), 0, stream>>>();
  fir_short_kernel<<<BLDSZ / 256, blk, 0, stream>>>(firs);
  fir_long_kernel<<<512, blk, 0, stream>>>(firl);
  stats_kernel<<<NBL * NH, dim3(64), 0, stream>>>();
  gate_kernel<<<NBL, blk, 0, stream>>>(W1, b1, W2, b2, ltp, bbs, crl);
  mix_rms_kernel<<<NBL, blk, 0, stream>>>(rw);
  hgemm_kernel<<<256, blk, 0, stream>>>(4, out);
}